// Round 1
// baseline (147.758 us; speedup 1.0000x reference)
//
#include <hip/hip_runtime.h>

// ChamferLoss: x,y [4, 8192, 3] fp32 -> scalar fp32.
// out = (sum_bn min_m d2 + sum_bm min_n d2) / 32768
// Strategy: 65536 "queries" (32768 x-points + 32768 y-points). Each query
// needs min over 8192 opposite points. Dot-product form with the query norm
// hoisted out of the inner loop: 5 VALU ops/pair. Opposite points are
// wave-uniform (broadcast loads), amortized over Q=4 queries per lane.

#define B_     4
#define N_     8192
#define NQH    32768        // queries per direction = B_*N_
#define SEGPTS 512          // N_ / 16 waves
#define FLT_BIG 3.0e38f

__global__ void zero_out_kernel(float* out) { *out = 0.0f; }

__global__ __launch_bounds__(256) void prep_kernel(
    const float* __restrict__ x, const float* __restrict__ y,
    float4* __restrict__ xext, float4* __restrict__ yext,
    float* __restrict__ out)
{
    int i = blockIdx.x * 256 + threadIdx.x;   // 0..65535 (grid 256)
    if (i == 0) *out = 0.0f;
    const float* src = (i < NQH) ? x : y;
    float4* dst      = (i < NQH) ? xext : yext;
    int j = i & (NQH - 1);
    float a = src[j*3+0], b = src[j*3+1], c = src[j*3+2];
    dst[j] = make_float4(a, b, c, fmaf(a, a, fmaf(b, b, c*c)));
}

template <bool EXT>
__global__ __launch_bounds__(1024) void chamfer_kernel(
    const float* __restrict__ xraw, const float* __restrict__ yraw,
    const float4* __restrict__ xext, const float4* __restrict__ yext,
    float* __restrict__ out)
{
    // Block covers 256 consecutive queries; wave w sweeps opposite segment w.
    __shared__ float4 red4[16][64];           // 16 KB: per-wave partial mins

    const int tid  = threadIdx.x;
    const int wave = tid >> 6;
    const int lane = tid & 63;
    const int blk  = blockIdx.x;              // 0..255
    const bool xdir = (blk < 128);            // first half: x queries vs y set
    const int b    = (blk & 127) >> 5;        // batch 0..3
    const int qofs = (blk & 31) << 8;         // query offset within batch
    const int bofs = b * N_;

    const float*  qraw = xdir ? xraw : yraw;
    const float4* qext = xdir ? xext : yext;
    const float*  oraw = xdir ? yraw : xraw;
    const float4* oext = xdir ? yext : xext;

    // Load this lane's 4 query points (qlocal = lane*4+q)
    float qx0[4], qx1[4], qx2[4], acc[4];
    #pragma unroll
    for (int q = 0; q < 4; ++q) {
        int qi = bofs + qofs + lane*4 + q;
        if (EXT) {
            float4 v = qext[qi];
            qx0[q] = v.x; qx1[q] = v.y; qx2[q] = v.z;
        } else {
            qx0[q] = qraw[qi*3+0]; qx1[q] = qraw[qi*3+1]; qx2[q] = qraw[qi*3+2];
        }
        acc[q] = FLT_BIG;
    }

    // Sweep this wave's 512-point segment of the opposite set.
    // acc[q] accumulates min_m (|y_m|^2 - 2 x_q . y_m); |x_q|^2 added at end.
    const int segBase = bofs + wave * SEGPTS;
    if (EXT) {
        const float4* opp = oext + segBase;
        #pragma unroll 4
        for (int k = 0; k < SEGPTS; ++k) {
            float4 p = opp[k];                       // wave-uniform broadcast
            #pragma unroll
            for (int q = 0; q < 4; ++q) {
                float dot = qx0[q]*p.x + qx1[q]*p.y + qx2[q]*p.z;
                float t   = fmaf(-2.0f, dot, p.w);
                acc[q] = fminf(acc[q], t);
            }
        }
    } else {
        const float* opp = oraw + (size_t)segBase * 3;
        #pragma unroll 4
        for (int k = 0; k < SEGPTS; ++k) {
            float p0 = opp[k*3+0], p1 = opp[k*3+1], p2 = opp[k*3+2];
            float w  = fmaf(p0, p0, fmaf(p1, p1, p2*p2));
            #pragma unroll
            for (int q = 0; q < 4; ++q) {
                float dot = qx0[q]*p0 + qx1[q]*p1 + qx2[q]*p2;
                float t   = fmaf(-2.0f, dot, w);
                acc[q] = fminf(acc[q], t);
            }
        }
    }

    red4[wave][lane] = make_float4(acc[0], acc[1], acc[2], acc[3]);
    __syncthreads();

    // Combine 16 segment-partials per query, add |x_q|^2, clamp, block-sum.
    if (tid < 256) {
        const float* red = (const float*)red4;     // red[w*256 + qlocal]
        float m = red[tid];
        #pragma unroll
        for (int w = 1; w < 16; ++w) m = fminf(m, red[w*256 + tid]);

        int qi = bofs + qofs + tid;
        float qn;
        if (EXT) {
            qn = qext[qi].w;
        } else {
            float a = qraw[qi*3+0], bb = qraw[qi*3+1], c = qraw[qi*3+2];
            qn = fmaf(a, a, fmaf(bb, bb, c*c));
        }
        float d2 = fmaxf(0.0f, qn + m);

        // width-64 wave reduction; 4 waves -> 4 atomics per block
        #pragma unroll
        for (int off = 32; off > 0; off >>= 1) d2 += __shfl_xor(d2, off);
        if ((tid & 63) == 0) atomicAdd(out, d2 * (1.0f / 32768.0f));
    }
}

extern "C" void kernel_launch(void* const* d_in, const int* in_sizes, int n_in,
                              void* d_out, int out_size, void* d_ws, size_t ws_size,
                              hipStream_t stream)
{
    const float* x = (const float*)d_in[0];
    const float* y = (const float*)d_in[1];
    float* out = (float*)d_out;

    const size_t need = (size_t)2 * NQH * sizeof(float4);   // 1 MiB ext arrays
    if (ws_size >= need) {
        float4* xext = (float4*)d_ws;
        float4* yext = xext + NQH;
        prep_kernel<<<256, 256, 0, stream>>>(x, y, xext, yext, out);
        chamfer_kernel<true><<<256, 1024, 0, stream>>>(x, y, xext, yext, out);
    } else {
        zero_out_kernel<<<1, 1, 0, stream>>>(out);
        chamfer_kernel<false><<<256, 1024, 0, stream>>>(x, y, nullptr, nullptr, out);
    }
}

// Round 2
// 126.161 us; speedup vs baseline: 1.1712x; 1.1712x over previous
//
#include <hip/hip_runtime.h>

// ChamferLoss: x,y [4, 8192, 3] fp32 -> scalar fp32.
// out = (sum_bn min_m d2 + sum_bm min_n d2) / 32768
//
// Round 2: packed-fp32 (v_pk_fma_f32) + v_min3_f32 inner loop.
// Prep kernel writes pair-packed records per 2 opposite points:
//   v0 = {x0,x1,y0,y1}, v1 = {z0,z1,w0,w1}  (w = |p|^2)
// so px2/py2/pz2/w2 are aligned VGPR pairs (no shuffle movs).
// Query regs pre-scaled by -2:  t2 = fma(qxm,px2, fma(qym,py2, fma(qzm,pz2, w2)))
// -> 3 pk_fma + 1 min3 per (2 points x 1 query) = 2 inst/pair math.

#define B_     4
#define N_     8192
#define NQH    32768        // queries per direction = B_*N_
#define PRB    4096         // pair-records per batch (N_/2)
#define NRECS  16384        // pair-records per side (B_*PRB)
#define FLT_BIG 3.0e38f

typedef float v2f __attribute__((ext_vector_type(2)));

__global__ void zero_out_kernel(float* out) { *out = 0.0f; }

// 128 blocks x 256: one thread per pair-record (2 sides x 16384 records).
__global__ __launch_bounds__(256) void prep_kernel(
    const float* __restrict__ x, const float* __restrict__ y,
    float4* __restrict__ xrec, float4* __restrict__ yrec,
    float* __restrict__ out)
{
    int i = blockIdx.x * 256 + threadIdx.x;   // 0..32767
    if (i == 0) *out = 0.0f;
    int side = i >> 14;
    int r    = i & (NRECS - 1);
    const float* src = side ? y : x;
    float4*      dst = side ? yrec : xrec;
    const float* p = src + (size_t)r * 6;     // 2 adjacent points, 6 floats
    float p0x = p[0], p0y = p[1], p0z = p[2];
    float p1x = p[3], p1y = p[4], p1z = p[5];
    float w0 = fmaf(p0x, p0x, fmaf(p0y, p0y, p0z * p0z));
    float w1 = fmaf(p1x, p1x, fmaf(p1y, p1y, p1z * p1z));
    dst[2*r]   = make_float4(p0x, p1x, p0y, p1y);
    dst[2*r+1] = make_float4(p0z, p1z, w0, w1);
}

// 256 blocks x 1024. Block covers 256 queries (Q=4 per lane); wave w sweeps
// 256 pair-records (512 points) of the opposite batch.
__global__ __launch_bounds__(1024) void chamfer_kernel(
    const float* __restrict__ xraw, const float* __restrict__ yraw,
    const float4* __restrict__ xrec, const float4* __restrict__ yrec,
    float* __restrict__ out)
{
    __shared__ float4 red4[16][64];           // 16 KB per-wave partial mins

    const int tid  = threadIdx.x;
    const int wave = tid >> 6;
    const int lane = tid & 63;
    const int blk  = blockIdx.x;              // 0..255
    const bool xdir = (blk < 128);            // x queries vs y set
    const int b    = (blk & 127) >> 5;        // batch 0..3
    const int qofs = (blk & 31) << 8;         // query offset in batch

    const float*  qraw = xdir ? xraw : yraw;
    const float4* orec = xdir ? yrec : xrec;

    // Per-lane queries, pre-scaled by -2, splatted into v2f pairs.
    v2f qxm[4], qym[4], qzm[4];
    float acc[4];
    #pragma unroll
    for (int q = 0; q < 4; ++q) {
        int gq = b * N_ + qofs + lane * 4 + q;
        float ax = qraw[gq*3+0], ay = qraw[gq*3+1], az = qraw[gq*3+2];
        qxm[q] = (v2f){-2.0f*ax, -2.0f*ax};
        qym[q] = (v2f){-2.0f*ay, -2.0f*ay};
        qzm[q] = (v2f){-2.0f*az, -2.0f*az};
        acc[q] = FLT_BIG;
    }

    // Sweep: 256 records (512 points), wave-uniform broadcast loads.
    const float4* rp = orec + (size_t)2 * (b * PRB + wave * 256);
    #pragma unroll 4
    for (int k = 0; k < 256; ++k) {
        float4 u = rp[2*k];                   // {x0,x1,y0,y1}
        float4 v = rp[2*k+1];                 // {z0,z1,w0,w1}
        v2f px2 = (v2f){u.x, u.y};
        v2f py2 = (v2f){u.z, u.w};
        v2f pz2 = (v2f){v.x, v.y};
        v2f w2  = (v2f){v.z, v.w};
        #pragma unroll
        for (int q = 0; q < 4; ++q) {
            // t = w - 2*(qx*px + qy*py + qz*pz), 2 points at once
            v2f t = qzm[q]*pz2 + w2;
            t = qym[q]*py2 + t;
            t = qxm[q]*px2 + t;
            acc[q] = fminf(acc[q], fminf(t.x, t.y));   // v_min3_f32
        }
    }

    red4[wave][lane] = make_float4(acc[0], acc[1], acc[2], acc[3]);
    __syncthreads();

    // Combine 16 wave-partials per query, add |q|^2, clamp, sum.
    if (tid < 256) {
        const float* red = (const float*)red4;     // red[w*256 + qlocal]
        float m = red[tid];
        #pragma unroll
        for (int w = 1; w < 16; ++w) m = fminf(m, red[w*256 + tid]);

        int gq = b * N_ + qofs + tid;
        float ax = qraw[gq*3+0], ay = qraw[gq*3+1], az = qraw[gq*3+2];
        float qn = fmaf(ax, ax, fmaf(ay, ay, az*az));
        float d2 = fmaxf(0.0f, qn + m);

        #pragma unroll
        for (int off = 32; off > 0; off >>= 1) d2 += __shfl_xor(d2, off);
        if ((tid & 63) == 0) atomicAdd(out, d2 * (1.0f / 32768.0f));
    }
}

// Fallback (ws too small): round-1 style raw-sweep kernel, known correct.
__global__ __launch_bounds__(1024) void chamfer_raw_kernel(
    const float* __restrict__ xraw, const float* __restrict__ yraw,
    float* __restrict__ out)
{
    __shared__ float4 red4[16][64];
    const int tid  = threadIdx.x;
    const int wave = tid >> 6;
    const int lane = tid & 63;
    const int blk  = blockIdx.x;
    const bool xdir = (blk < 128);
    const int b    = (blk & 127) >> 5;
    const int qofs = (blk & 31) << 8;
    const float* qraw = xdir ? xraw : yraw;
    const float* oraw = xdir ? yraw : xraw;

    float qx0[4], qx1[4], qx2[4], acc[4];
    #pragma unroll
    for (int q = 0; q < 4; ++q) {
        int gq = b * N_ + qofs + lane*4 + q;
        qx0[q] = qraw[gq*3+0]; qx1[q] = qraw[gq*3+1]; qx2[q] = qraw[gq*3+2];
        acc[q] = FLT_BIG;
    }
    const float* opp = oraw + (size_t)(b * N_ + wave * 512) * 3;
    #pragma unroll 4
    for (int k = 0; k < 512; ++k) {
        float p0 = opp[k*3+0], p1 = opp[k*3+1], p2 = opp[k*3+2];
        float w  = fmaf(p0, p0, fmaf(p1, p1, p2*p2));
        #pragma unroll
        for (int q = 0; q < 4; ++q) {
            float dot = qx0[q]*p0 + qx1[q]*p1 + qx2[q]*p2;
            acc[q] = fminf(acc[q], fmaf(-2.0f, dot, w));
        }
    }
    red4[wave][lane] = make_float4(acc[0], acc[1], acc[2], acc[3]);
    __syncthreads();
    if (tid < 256) {
        const float* red = (const float*)red4;
        float m = red[tid];
        #pragma unroll
        for (int w = 1; w < 16; ++w) m = fminf(m, red[w*256 + tid]);
        int gq = b * N_ + qofs + tid;
        float ax = qraw[gq*3+0], ay = qraw[gq*3+1], az = qraw[gq*3+2];
        float d2 = fmaxf(0.0f, fmaf(ax,ax,fmaf(ay,ay,az*az)) + m);
        #pragma unroll
        for (int off = 32; off > 0; off >>= 1) d2 += __shfl_xor(d2, off);
        if ((tid & 63) == 0) atomicAdd(out, d2 * (1.0f / 32768.0f));
    }
}

extern "C" void kernel_launch(void* const* d_in, const int* in_sizes, int n_in,
                              void* d_out, int out_size, void* d_ws, size_t ws_size,
                              hipStream_t stream)
{
    const float* x = (const float*)d_in[0];
    const float* y = (const float*)d_in[1];
    float* out = (float*)d_out;

    const size_t need = (size_t)2 * NRECS * 2 * sizeof(float4);   // 1 MiB
    if (ws_size >= need) {
        float4* xrec = (float4*)d_ws;
        float4* yrec = xrec + 2 * NRECS;
        prep_kernel<<<128, 256, 0, stream>>>(x, y, xrec, yrec, out);
        chamfer_kernel<<<256, 1024, 0, stream>>>(x, y, xrec, yrec, out);
    } else {
        zero_out_kernel<<<1, 1, 0, stream>>>(out);
        chamfer_raw_kernel<<<256, 1024, 0, stream>>>(x, y, out);
    }
}